// Round 5
// baseline (828.162 us; speedup 1.0000x reference)
//
#include <hip/hip_runtime.h>
#include <hip/hip_bf16.h>
#include <math.h>

typedef __attribute__((ext_vector_type(4))) float f32x4;
typedef __attribute__((ext_vector_type(8))) short s16x8;

#define LOG2E 1.4426950408889634f
#define LN2f  0.6931471805599453f
#define INV_E 0.36787944117144233f

__device__ __forceinline__ short bfc(float x) {
  unsigned u = __float_as_uint(x);
  unsigned r = u + 0x7fffu + ((u >> 16) & 1u);   // RNE to bf16
  return (short)(r >> 16);
}

__device__ __forceinline__ unsigned pk2(float x, float y) {
  union { __hip_bfloat162 h; unsigned u; } c;
  c.h = __float22bfloat162_rn(make_float2(x, y));  // v_cvt_pk_bf16_f32
  return c.u;
}

__device__ __forceinline__ float rdlane(float v, int lane) {
  return __int_as_float(__builtin_amdgcn_readlane(__float_as_int(v), lane));
}

__device__ __forceinline__ float pick9(int j, float a0, float a1, float a2,
                                       float a3, float a4, float a5, float a6,
                                       float a7, float a8) {
  float v = a0;
  if (j == 1) v = a1;
  if (j == 2) v = a2;
  if (j == 3) v = a3;
  if (j == 4) v = a4;
  if (j == 5) v = a5;
  if (j == 6) v = a6;
  if (j == 7) v = a7;
  if (j == 8) v = a8;
  return v;
}

// async global -> LDS, 16B per lane: LDS dest = uniform base + lane*16,
// global src per-lane. [m03/m97/m173]
__device__ __forceinline__ void gload_lds16(const float* g, float* l) {
  __builtin_amdgcn_global_load_lds(
      (const __attribute__((address_space(1))) unsigned int*)g,
      (__attribute__((address_space(3))) unsigned int*)l, 16, 0, 0);
}

// ---------------------------------------------------------------------------
// Kernel 0: W (V x D fp32) -> Wb (64 x D bf16), rows >= V zero-filled.
// Also zeroes the producer/consumer flags.
// ---------------------------------------------------------------------------
__global__ void conv_w(const float* __restrict__ W, short* __restrict__ Wb,
                       int V, int D, int* __restrict__ flags, int nflags) {
  int idx = blockIdx.x * blockDim.x + threadIdx.x;
  if (idx < nflags) flags[idx] = 0;
  if (idx >= 64 * D) return;
  int row = idx / D, col = idx - row * D;
  Wb[idx] = (row < V) ? bfc(W[(size_t)row * D + col]) : (short)0;
}

// ---------------------------------------------------------------------------
// Fused kernel v5: producer identical to v4. Consumer DP rewritten around an
// LDS-staged ring (r4 occupancy math: producer span ~150us, DP tail ~368us
// at 430 cyc/step == one memory latency per pair -> compiler vmcnt(0)-drains
// the register ring). New consumer:
//   - 32-slot LDS row ring (32KB), staged 24 rows ahead with global_load_lds
//     dwordx4 (1 instr/row, fire-and-forget, vmcnt-counted)
//   - 4-slot LDS chunk ring for (star~, K) scalars (4KB, 1 instr per 128-row
//     chunk, drained at the 16 chunk crossings)
//   - steady state: issue 8 rows, s_waitcnt vmcnt(24) (3 iters in flight,
//     in-order vmcnt [m135] makes the count exact), consume 8 rows via
//     ds_read_b128/b64 (compiler's counted lgkmcnt is near-optimal)
// Sync: per-(b,c) flag RELEASE; consumer polls RELAXED agent-scope + one
// acquire fence per chunk crossing (before any staging of that chunk).
// ---------------------------------------------------------------------------
__global__ __launch_bounds__(256, 2) void fused_gemm_star(
    const float* __restrict__ feat, const short* __restrict__ Wb,
    const float* __restrict__ bias, float* __restrict__ ptg,
    float* __restrict__ skb, int* __restrict__ flags,
    const int* __restrict__ targets, const int* __restrict__ in_len,
    const int* __restrict__ tgt_len, float* __restrict__ partial,
    int nrows, int D, int V, int T, int S, int B, int CPB) {

  // consumer: [0,32768) row ring (32 x 256 f32), [32768,36864) sk ring
  // producer: first 4KB = gbuf[4][4][64]
  __shared__ __align__(16) char smem[36864];

  if ((int)blockIdx.x >= B) {
    // ===================== one-shot producer (one tile) ===================
    typedef float GB[4][64];
    GB* gbuf = (GB*)smem;
    const int j = blockIdx.x - B;
    const int c = j / B;
    const int b = j - c * B;
    const int tc0 = c * 128;
    const int rlen = (T - tc0 < 128) ? (T - tc0) : 128;
    const int rowlim = b * T + tc0 + rlen;

    const int lane = threadIdx.x & 63;
    const int wave = threadIdx.x >> 6;
    const int m_lo = lane & 15;
    const int q = lane >> 4;
    const size_t bstr = (size_t)16 * D;
    const int rowbase = b * T + tc0 + wave * 32;

    const int* tg = targets + (size_t)b * S;
    const int l0 = lane * 4;
    const int g1 = (l0 < S) ? tg[l0] : 0;
    const int g3 = (l0 + 1 < S) ? tg[l0 + 1] : 0;
    const int g5 = (l0 + 2 < S) ? tg[l0 + 2] : 0;
    const int g7 = (l0 + 3 < S) ? tg[l0 + 3] : 0;

    int arow0 = rowbase + m_lo;
    int arow1 = rowbase + 16 + m_lo;
    if (arow0 >= nrows) arow0 = nrows - 1;
    if (arow1 >= nrows) arow1 = nrows - 1;
    const float* A0base = feat + (size_t)arow0 * D + q * 8;
    const float* A1base = feat + (size_t)arow1 * D + q * 8;
    const short* Bbase = Wb + (size_t)m_lo * D + q * 8;

    f32x4 acc[2][4];
    #pragma unroll
    for (int g = 0; g < 2; ++g)
      #pragma unroll
      for (int ni = 0; ni < 4; ++ni) acc[g][ni] = (f32x4){0.f, 0.f, 0.f, 0.f};

#define DECLS(s) float4 al0_##s, ah0_##s, al1_##s, ah1_##s;                  \
                 s16x8 b0_##s, b1_##s, b2_##s, b3_##s
    DECLS(0); DECLS(1); DECLS(2); DECLS(3);
#undef DECLS

#define LOADS(s, kk)                                                         \
  do {                                                                       \
    const float* A0p = A0base + (kk);                                        \
    const float* A1p = A1base + (kk);                                        \
    const short* Bpp = Bbase + (kk);                                         \
    al0_##s = *(const float4*)(A0p);                                         \
    ah0_##s = *(const float4*)(A0p + 4);                                     \
    al1_##s = *(const float4*)(A1p);                                         \
    ah1_##s = *(const float4*)(A1p + 4);                                     \
    b0_##s = *(const s16x8*)(Bpp);                                           \
    b1_##s = *(const s16x8*)(Bpp + bstr);                                    \
    b2_##s = *(const s16x8*)(Bpp + 2 * bstr);                                \
    b3_##s = *(const s16x8*)(Bpp + 3 * bstr);                                \
  } while (0)

#define COMPUTE(s)                                                           \
  do {                                                                       \
    union { s16x8 v; unsigned u[4]; } av0, av1;                              \
    av0.u[0] = pk2(al0_##s.x, al0_##s.y);                                    \
    av0.u[1] = pk2(al0_##s.z, al0_##s.w);                                    \
    av0.u[2] = pk2(ah0_##s.x, ah0_##s.y);                                    \
    av0.u[3] = pk2(ah0_##s.z, ah0_##s.w);                                    \
    av1.u[0] = pk2(al1_##s.x, al1_##s.y);                                    \
    av1.u[1] = pk2(al1_##s.z, al1_##s.w);                                    \
    av1.u[2] = pk2(ah1_##s.x, ah1_##s.y);                                    \
    av1.u[3] = pk2(ah1_##s.z, ah1_##s.w);                                    \
    acc[0][0] = __builtin_amdgcn_mfma_f32_16x16x32_bf16(av0.v, b0_##s, acc[0][0], 0, 0, 0); \
    acc[0][1] = __builtin_amdgcn_mfma_f32_16x16x32_bf16(av0.v, b1_##s, acc[0][1], 0, 0, 0); \
    acc[0][2] = __builtin_amdgcn_mfma_f32_16x16x32_bf16(av0.v, b2_##s, acc[0][2], 0, 0, 0); \
    acc[0][3] = __builtin_amdgcn_mfma_f32_16x16x32_bf16(av0.v, b3_##s, acc[0][3], 0, 0, 0); \
    acc[1][0] = __builtin_amdgcn_mfma_f32_16x16x32_bf16(av1.v, b0_##s, acc[1][0], 0, 0, 0); \
    acc[1][1] = __builtin_amdgcn_mfma_f32_16x16x32_bf16(av1.v, b1_##s, acc[1][1], 0, 0, 0); \
    acc[1][2] = __builtin_amdgcn_mfma_f32_16x16x32_bf16(av1.v, b2_##s, acc[1][2], 0, 0, 0); \
    acc[1][3] = __builtin_amdgcn_mfma_f32_16x16x32_bf16(av1.v, b3_##s, acc[1][3], 0, 0, 0); \
  } while (0)

    LOADS(0, 0); LOADS(1, 32); LOADS(2, 64); LOADS(3, 96);
    for (int k0 = 0; k0 < D; k0 += 128) {
      { COMPUTE(0); int kp = k0 + 128; if (kp >= D) kp = 0;  LOADS(0, kp); }
      { COMPUTE(1); int kp = k0 + 160; if (kp >= D) kp = 32; LOADS(1, kp); }
      { COMPUTE(2); int kp = k0 + 192; if (kp >= D) kp = 64; LOADS(2, kp); }
      { COMPUTE(3); int kp = k0 + 224; if (kp >= D) kp = 96; LOADS(3, kp); }
    }
#undef LOADS
#undef COMPUTE

    float bias_v[4];
    #pragma unroll
    for (int ni = 0; ni < 4; ++ni) {
      int col = ni * 16 + m_lo;
      bias_v[ni] = (col < V) ? bias[col] : 0.f;
    }

    // C/D layout: col = lane&15, row = (lane>>4)*4 + reg   [m89-verified]
    #pragma unroll
    for (int g = 0; g < 2; ++g) {
      #pragma unroll
      for (int r = 0; r < 4; ++r) {
        float lg[4];
        #pragma unroll
        for (int ni = 0; ni < 4; ++ni) {
          int col = ni * 16 + m_lo;
          lg[ni] = (col < V) ? (acc[g][ni][r] + bias_v[ni]) : -1e30f;
        }
        float m = fmaxf(fmaxf(lg[0], lg[1]), fmaxf(lg[2], lg[3]));
        #pragma unroll
        for (int off = 1; off < 16; off <<= 1) m = fmaxf(m, __shfl_xor(m, off));
        float p[4];
        #pragma unroll
        for (int ni = 0; ni < 4; ++ni) p[ni] = exp2f((lg[ni] - m) * LOG2E);
        float s = (p[0] + p[1]) + (p[2] + p[3]);
        #pragma unroll
        for (int off = 1; off < 16; off <<= 1) s += __shfl_xor(s, off);

        #pragma unroll
        for (int ni = 0; ni < 4; ++ni)
          gbuf[wave][q][ni * 16 + m_lo] = p[ni];

        #pragma unroll
        for (int rr = 0; rr < 4; ++rr) {
          int grow = rowbase + g * 16 + rr * 4 + r;
          if (grow < rowlim) {
            float srow = rdlane(s, rr * 16);
            float4 ev;
            ev.x = gbuf[wave][rr][g1];
            ev.y = gbuf[wave][rr][g3];
            ev.z = gbuf[wave][rr][g5];
            ev.w = gbuf[wave][rr][g7];
            *(float4*)(ptg + ((size_t)grow * 64 + lane) * 4) = ev;
            if (lane == 0) {
              float2 skv;
              skv.x = srow * INV_E;      // star~ emission
              skv.y = logf(srow);       // K_t (ln units)
              *(float2*)(skb + (size_t)grow * 2) = skv;
            }
          }
        }
      }
    }

    __syncthreads();
    if (threadIdx.x == 0)
      __hip_atomic_store(&flags[b * CPB + c], 1, __ATOMIC_RELEASE,
                         __HIP_MEMORY_SCOPE_AGENT);
    return;
  }

  // ================= consumer: star-CTC DP (1 wave / sequence) =============
  if (threadIdx.x >= 64) return;
  const int n = blockIdx.x;
  const int lane = threadIdx.x;
  const int len = in_len[n];
  const int tl = tgt_len[n];
  const int* tg = targets + (size_t)n * S;
  const int* fl = flags + n * CPB;
  const float* prow = ptg + (size_t)n * T * 256;
  const float* srow = skb + (size_t)n * T * 2;

  float* ring = (float*)smem;                 // 32 slots x 256 f32
  float* sklr = (float*)(smem + 32768);       // 4 chunks x 256 f32

  int cdone = -1;
#define WAITC(cc)                                                            \
  do {                                                                       \
    int _c = (cc);                                                           \
    if (cdone < _c) {                                                        \
      while (cdone < _c) {                                                   \
        if (__hip_atomic_load((int*)&fl[cdone + 1], __ATOMIC_RELAXED,        \
                              __HIP_MEMORY_SCOPE_AGENT))                     \
          ++cdone;                                                           \
        else                                                                 \
          __builtin_amdgcn_s_sleep(8);                                       \
      }                                                                      \
      __builtin_amdgcn_fence(__ATOMIC_ACQUIRE, "agent");                     \
    }                                                                        \
  } while (0)

  // stage one emission row (1KB) into ring slot t&31 (clamped source)
#define STAGE_ROW(t)                                                         \
  do {                                                                       \
    int _tt = ((t) < len) ? (t) : (len - 1);                                 \
    gload_lds16(prow + ((size_t)_tt << 8) + (lane << 2),                     \
                ring + (((t) & 31) << 8));                                   \
  } while (0)

  // stage one chunk (128 rows) of (star~, K) scalars into sk ring slot c&3
#define STAGE_SK(c)                                                          \
  gload_lds16(srow + ((size_t)(c) << 8) + (lane << 2),                       \
              sklr + (((c) & 3) << 8))

#define EROW(t) (*(const float4*)(ring + (((t) & 31) << 8) + (lane << 2)))

  const int s0 = lane * 4;
  int lab1 = (s0     < S) ? tg[s0]     : 0;
  int lab3 = (s0 + 1 < S) ? tg[s0 + 1] : 0;
  int lab5 = (s0 + 2 < S) ? tg[s0 + 2] : 0;
  int lab7 = (s0 + 3 < S) ? tg[s0 + 3] : 0;
  int labm1 = __shfl_up(lab7, 1);
  int labm3 = __shfl_up(lab5, 1);
  const bool sk1 = (lane > 0) && (lab1 != labm1);
  const bool sk3 = (lab3 != lab1);
  const bool sk5 = (lab5 != lab3);
  const bool sk7 = (lab7 != lab5);
  const bool skm1 = (labm1 != labm3);

  float a0 = 0, a1 = 0, a2 = 0, a3 = 0, a4 = 0, a5 = 0, a6 = 0, a7 = 0, a8 = 0;
  float m1 = 0.f, m2 = 0.f, m3 = 0.f;
  int eps = 0, eL = 0;
  bool act = (lane == 0);

  // sk row read (broadcast, clamped)
  #define KROW(t) krowf(sklr, (t), len)
  struct KR { __device__ static float2 f(const float* sklr, int t, int len) {
    int tt = (t < len) ? t : (len - 1);
    return *(const float2*)(sklr + (((tt >> 7) & 3) << 8) + ((tt & 127) << 1));
  } };
  #undef KROW
#define KROW(t) KR::f(sklr, (t), len)

  // ---- prologue: chunk 0 flag, stage sk0 + rows 0..23, drain ----
  WAITC(0);
  STAGE_SK(0);
  #pragma unroll
  for (int t = 0; t < 24; ++t) STAGE_ROW(t);
  asm volatile("s_waitcnt vmcnt(0)" ::: "memory");

  float4 r0v = EROW(0);
  float2 q0v = KROW(0);
  if (lane == 0) { a0 = q0v.x; a1 = r0v.x; }     // star~, e1 = p[tg[0]]
  float ksum = q0v.y;

#define RENORM()                                                             \
  do {                                                                       \
    float mx = fmaxf(fmaxf(fmaxf(a0, a1), fmaxf(a2, a3)),                    \
                     fmaxf(fmaxf(a4, a5), fmaxf(a6, a7)));                   \
    mx = fmaxf(mx, a8);                                                      \
    int e = (int)((__float_as_uint(mx) >> 23) & 255) - 126;                  \
    e = (act && mx > 0.f) ? e : 0;                                           \
    a0 = ldexpf(a0, -e); a1 = ldexpf(a1, -e); a2 = ldexpf(a2, -e);           \
    a3 = ldexpf(a3, -e); a4 = ldexpf(a4, -e); a5 = ldexpf(a5, -e);           \
    a6 = ldexpf(a6, -e); a7 = ldexpf(a7, -e); a8 = ldexpf(a8, -e);           \
    eps += e;                                                                \
  } while (0)

#define PAIR(EA, EB, KA, KB, DOREN)                                          \
  do {                                                                       \
    float em1a = __shfl_up(EA.w, 1);                                         \
    ksum += KA.y; ksum += KB.y;                                              \
    if (!act) eps = eL;                                                      \
    bool inc = (lane != 0) &&                                                \
               ((m1 != 0.f) || (m2 != 0.f) || (m3 != 0.f));                  \
    int d = inc ? (eL - eps) : 0;                                            \
    if (__builtin_expect(d > 24, 0)) {            /* raise own frame */      \
      a0 = ldexpf(a0, -d); a1 = ldexpf(a1, -d); a2 = ldexpf(a2, -d);         \
      a3 = ldexpf(a3, -d); a4 = ldexpf(a4, -d); a5 = ldexpf(a5, -d);         \
      a6 = ldexpf(a6, -d); a7 = ldexpf(a7, -d); a8 = ldexpf(a8, -d);         \
      eps += d;                                   /* m stay in frame eL */   \
    } else {                                                                 \
      m1 = ldexpf(m1, d); m2 = ldexpf(m2, d); m3 = ldexpf(m3, d);            \
    }                                                                        \
    act = act || (m1 != 0.f) || (m2 != 0.f) || (m3 != 0.f);                  \
    /* sub-step 1 (in-place top-down; uses old lower states) */              \
    a8 = (a8 + a7) * KA.x;                                                   \
    a7 = (a7 + a6 + (sk7 ? a5 : 0.f)) * EA.w;                                \
    a6 = (a6 + a5) * KA.x;                                                   \
    a5 = (a5 + a4 + (sk5 ? a3 : 0.f)) * EA.z;                                \
    a4 = (a4 + a3) * KA.x;                                                   \
    a3 = (a3 + a2 + (sk3 ? a1 : 0.f)) * EA.y;                                \
    a2 = (a2 + a1) * KA.x;                                                   \
    a1 = (a1 + a0 + (sk1 ? m1 : 0.f)) * EA.x;                                \
    a0 = (a0 + m1) * KA.x;                                                   \
    m1 = (m1 + m2 + (skm1 ? m3 : 0.f)) * em1a;                               \
    /* sub-step 2 */                                                         \
    a8 = (a8 + a7) * KB.x;                                                   \
    a7 = (a7 + a6 + (sk7 ? a5 : 0.f)) * EB.w;                                \
    a6 = (a6 + a5) * KB.x;                                                   \
    a5 = (a5 + a4 + (sk5 ? a3 : 0.f)) * EB.z;                                \
    a4 = (a4 + a3) * KB.x;                                                   \
    a3 = (a3 + a2 + (sk3 ? a1 : 0.f)) * EB.y;                                \
    a2 = (a2 + a1) * KB.x;                                                   \
    a1 = (a1 + a0 + (sk1 ? m1 : 0.f)) * EB.x;                                \
    a0 = (a0 + m1) * KB.x;                                                   \
    if (DOREN) RENORM();                                                     \
    m3 = __shfl_up(a5, 1); m2 = __shfl_up(a6, 1); m1 = __shfl_up(a7, 1);     \
    eL = __shfl_up(eps, 1);                                                  \
    if (lane == 0) { m1 = 0.f; m2 = 0.f; m3 = 0.f; }                         \
  } while (0)

  int t0 = 1, cstage = 0;
  for (; t0 + 8 <= len; t0 += 8) {
    int tg2 = t0 + 31; if (tg2 > len - 1) tg2 = len - 1;
    int cg = tg2 >> 7;
    if (cg > cdone) {                            // chunk crossing (x16/seq)
      WAITC(cg);
      for (int cc = cstage + 1; cc <= cg; ++cc) STAGE_SK(cc);
      cstage = cg;
      asm volatile("s_waitcnt vmcnt(0)" ::: "memory");
    }
    // issue next group (rows t0+24..t0+31) into freed ring slots
    STAGE_ROW(t0 + 24); STAGE_ROW(t0 + 25);
    STAGE_ROW(t0 + 26); STAGE_ROW(t0 + 27);
    STAGE_ROW(t0 + 28); STAGE_ROW(t0 + 29);
    STAGE_ROW(t0 + 30); STAGE_ROW(t0 + 31);
    // group t0..t0+7 was issued 3 iterations (24 loads) ago -> complete
    asm volatile("s_waitcnt vmcnt(24)" ::: "memory");
    float4 E0 = EROW(t0),     E1 = EROW(t0 + 1);
    float4 E2 = EROW(t0 + 2), E3 = EROW(t0 + 3);
    float4 E4 = EROW(t0 + 4), E5 = EROW(t0 + 5);
    float4 E6 = EROW(t0 + 6), E7 = EROW(t0 + 7);
    float2 Q0 = KROW(t0),     Q1 = KROW(t0 + 1);
    float2 Q2 = KROW(t0 + 2), Q3 = KROW(t0 + 3);
    float2 Q4 = KROW(t0 + 4), Q5 = KROW(t0 + 5);
    float2 Q6 = KROW(t0 + 6), Q7 = KROW(t0 + 7);
    PAIR(E0, E1, Q0, Q1, false);
    PAIR(E2, E3, Q2, Q3, false);
    PAIR(E4, E5, Q4, Q5, false);
    PAIR(E6, E7, Q6, Q7, true);                  // t0+7 == 0 mod 8
  }

  {                                              // cover tail chunks
    int cg = (len - 1) >> 7;
    if (cg > cdone) {
      WAITC(cg);
      for (int cc = cstage + 1; cc <= cg; ++cc) STAGE_SK(cc);
      cstage = cg;
    }
  }
  asm volatile("s_waitcnt vmcnt(0)" ::: "memory");

  // tail: <= 7 single steps
  for (int t = t0; t < len; ++t) {
    float4 cv = EROW(t);
    float2 kc = KROW(t);
    ksum += kc.y;
    if (!act) eps = eL;
    bool inc = (lane != 0) && (m1 != 0.f);
    int d = inc ? (eL - eps) : 0;
    float m1s;
    if (__builtin_expect(d > 24, 0)) {
      a0 = ldexpf(a0, -d); a1 = ldexpf(a1, -d); a2 = ldexpf(a2, -d);
      a3 = ldexpf(a3, -d); a4 = ldexpf(a4, -d); a5 = ldexpf(a5, -d);
      a6 = ldexpf(a6, -d); a7 = ldexpf(a7, -d); a8 = ldexpf(a8, -d);
      eps += d; m1s = m1;
    } else {
      m1s = inc ? ldexpf(m1, d) : 0.f;
    }
    act = act || (m1s != 0.f);
    a8 = (a8 + a7) * kc.x;
    a7 = (a7 + a6 + (sk7 ? a5 : 0.f)) * cv.w;
    a6 = (a6 + a5) * kc.x;
    a5 = (a5 + a4 + (sk5 ? a3 : 0.f)) * cv.z;
    a4 = (a4 + a3) * kc.x;
    a3 = (a3 + a2 + (sk3 ? a1 : 0.f)) * cv.y;
    a2 = (a2 + a1) * kc.x;
    a1 = (a1 + a0 + (sk1 ? m1s : 0.f)) * cv.x;
    a0 = (a0 + m1s) * kc.x;
    if ((t & 7) == 0) RENORM();
    m1 = __shfl_up(a7, 1);
    eL = __shfl_up(eps, 1);
    if (lane == 0) m1 = 0.f;
  }

  // final reduce — all cross-lane via shfl (no barrier)
  int last = 2 * tl;
  int kx = last >> 3, jx = last & 7;
  if (kx > 63) { kx = 63; jx = last - 504; }     // state 512 -> lane63 a8
  int ky = (last - 1) >> 3, jy = (last - 1) & 7;
  float vx = pick9(jx, a0, a1, a2, a3, a4, a5, a6, a7, a8);
  float vy = pick9(jy, a0, a1, a2, a3, a4, a5, a6, a7, a8);
  float sx = __shfl(vx, kx); int ex = __shfl(eps, kx);
  float sy = __shfl(vy, ky); int ey = __shfl(eps, ky);
  if (lane == 0) {
    int em = (ex > ey) ? ex : ey;
    float v = ldexpf(sx, ex - em) + ldexpf(sy, ey - em);
    float score = logf(v) + (float)em * LN2f - ksum;
    partial[n] = -score / (float)tl;
  }
#undef WAITC
#undef STAGE_ROW
#undef STAGE_SK
#undef EROW
#undef KROW
#undef RENORM
#undef PAIR
}

// ---------------------------------------------------------------------------
// Kernel 3: mean over batch
// ---------------------------------------------------------------------------
__global__ void reduce_mean(const float* __restrict__ partial,
                            float* __restrict__ out, int B) {
  float v = 0.f;
  for (int i = threadIdx.x; i < B; i += 64) v += partial[i];
  #pragma unroll
  for (int off = 32; off > 0; off >>= 1) v += __shfl_down(v, off, 64);
  if (threadIdx.x == 0) out[0] = v / (float)B;
}

extern "C" void kernel_launch(void* const* d_in, const int* in_sizes, int n_in,
                              void* d_out, int out_size, void* d_ws, size_t ws_size,
                              hipStream_t stream) {
  const float* feat = (const float*)d_in[0];
  const float* W = (const float*)d_in[1];
  const float* bias = (const float*)d_in[2];
  const int* targets = (const int*)d_in[3];
  const int* in_len = (const int*)d_in[4];
  const int* tgt_len = (const int*)d_in[5];
  float* out = (float*)d_out;

  const int V = in_sizes[2];
  const int D = in_sizes[1] / V;
  const int B = in_sizes[4];
  const int T = in_sizes[0] / (B * D);
  const int S = in_sizes[3] / B;
  const int nrows = B * T;

  float* ptg = (float*)d_ws;                        // nrows*256 fp32 (64 MB)
  float* skb = ptg + (size_t)nrows * 256;           // nrows*2 fp32
  float* partial = skb + (size_t)nrows * 2;         // B fp32
  short* Wb = (short*)(partial + B);                // 64*D bf16
  const int CPB = (T + 127) / 128;                  // time-chunks per batch
  int* flags = (int*)((char*)Wb + (size_t)64 * D * sizeof(short));  // B*CPB

  conv_w<<<(64 * D + 255) / 256, 256, 0, stream>>>(W, Wb, V, D,
                                                   flags, B * CPB);

  const int NTILES = B * CPB;
  fused_gemm_star<<<dim3(B + NTILES), 256, 0, stream>>>(
      feat, Wb, bias, ptg, skb, flags, targets, in_len, tgt_len, partial,
      nrows, D, V, T, S, B, CPB);

  reduce_mean<<<1, 64, 0, stream>>>(partial, out, B);
}

// Round 6
// 670.712 us; speedup vs baseline: 1.2347x; 1.2347x over previous
//
#include <hip/hip_runtime.h>
#include <hip/hip_bf16.h>
#include <math.h>

typedef __attribute__((ext_vector_type(4))) float f32x4;
typedef __attribute__((ext_vector_type(8))) short s16x8;

#define LOG2E 1.4426950408889634f
#define LN2f  0.6931471805599453f
#define INV_E 0.36787944117144233f

__device__ __forceinline__ short bfc(float x) {
  unsigned u = __float_as_uint(x);
  unsigned r = u + 0x7fffu + ((u >> 16) & 1u);   // RNE to bf16
  return (short)(r >> 16);
}

__device__ __forceinline__ unsigned pk2(float x, float y) {
  union { __hip_bfloat162 h; unsigned u; } c;
  c.h = __float22bfloat162_rn(make_float2(x, y));  // v_cvt_pk_bf16_f32
  return c.u;
}

__device__ __forceinline__ float bperm(float v, int byte_addr) {
  return __int_as_float(__builtin_amdgcn_ds_bpermute(byte_addr, __float_as_int(v)));
}

__device__ __forceinline__ float rdlane(float v, int lane) {
  return __int_as_float(__builtin_amdgcn_readlane(__float_as_int(v), lane));
}

__device__ __forceinline__ float pick9(int j, float a0, float a1, float a2,
                                       float a3, float a4, float a5, float a6,
                                       float a7, float a8) {
  float v = a0;
  if (j == 1) v = a1;
  if (j == 2) v = a2;
  if (j == 3) v = a3;
  if (j == 4) v = a4;
  if (j == 5) v = a5;
  if (j == 6) v = a6;
  if (j == 7) v = a7;
  if (j == 8) v = a8;
  return v;
}

// async global -> LDS, 16B/lane: LDS dest = wave-uniform base + lane*16,
// global src per-lane [m03/m97/m104/m173]
__device__ __forceinline__ void gload_lds16(const float* g, float* l) {
  __builtin_amdgcn_global_load_lds(
      (const __attribute__((address_space(1))) unsigned int*)g,
      (__attribute__((address_space(3))) unsigned int*)l, 16, 0, 0);
}

// ---------------------------------------------------------------------------
// Kernel 0: W (V x D fp32) -> Wb (64 x D bf16), rows >= V zero-filled.
// Also zeroes the producer/consumer flags.
// ---------------------------------------------------------------------------
__global__ void conv_w(const float* __restrict__ W, short* __restrict__ Wb,
                       int V, int D, int* __restrict__ flags, int nflags) {
  int idx = blockIdx.x * blockDim.x + threadIdx.x;
  if (idx < nflags) flags[idx] = 0;
  if (idx >= 64 * D) return;
  int row = idx / D, col = idx - row * D;
  Wb[idx] = (row < V) ? bfc(W[(size_t)row * D + col]) : (short)0;
}

// ---------------------------------------------------------------------------
// Fused kernel v6.
// Post-mortem r5: DP time tracks ring-row BYTES (256B->333us, 1KB->368/418)
// -> revert consumer to the r1 bperm/256B-row version (fastest measured).
// Producer ~150us is DRAM-page thrash: 64-128B per 4KB-strided row (measured
// 1.07 TB/s == random-64B ceiling). v6 producer stages per-wave A-panels
// (32 rows x BK=128 f32) to LDS with global_load_lds: 512B CONTIGUOUS per
// row per stage (8x per-page transfer), 16 fire-and-forget 1KB instrs in
// flight, per-wave private panel -> NO barriers in the k-loop (per-wave
// vmcnt(0) only). LDS reads: T2 XOR swizzle, both sides (pre-swizzled
// global source per m173; swizzled ds_read_b128) -> 2-way conflicts (free).
//   blocks [0, B)      : star-CTC DP consumer (1 wave; rest return)
//   blocks [B, B+128)  : persistent producers, c-major tile walk (4 tiles
//                        each) -> chunk wavefront: chunks 0-3 at ~1 round,
//                        4-7 at 2, ... DP pace ~21us/chunk stays behind.
// Sync unchanged: per-(b,c) flag RELEASE; relaxed agent-scope poll + one
// acquire fence per chunk crossing.
// ---------------------------------------------------------------------------
__global__ __launch_bounds__(256) void fused_gemm_star(
    const float* __restrict__ feat, const short* __restrict__ Wb,
    const float* __restrict__ bias, float* __restrict__ pt,
    int* __restrict__ flags,
    const int* __restrict__ targets, const int* __restrict__ in_len,
    const int* __restrict__ tgt_len, float* __restrict__ partial,
    int nrows, int D, int V, int T, int S, int B, int CPB) {

  // per-wave A panels: [wave][32 rows][128 f32] = 64 KB total
  __shared__ __align__(16) float Ap[4 * 32 * 128];

  if ((int)blockIdx.x >= B) {
    // ======================= persistent producer ==========================
    const int NPROD = gridDim.x - B;
    const int NTILES = B * CPB;
    const int lane = threadIdx.x & 63;
    const int wave = threadIdx.x >> 6;
    const int m_lo = lane & 15;
    const int q = lane >> 4;
    float* wpan = Ap + wave * 32 * 128;            // this wave's panel
    char* wpanb = (char*)wpan;

    for (int i = blockIdx.x - B; i < NTILES; i += NPROD) {
      const int c = i / B;
      const int b = i - c * B;
      const int tc0 = c * 128;
      const int rlen = (T - tc0 < 128) ? (T - tc0) : 128;
      const int rowlim = b * T + tc0 + rlen;
      const int rowbase = b * T + tc0 + wave * 32; // this wave's 32 rows

      f32x4 acc[2][4];
      #pragma unroll
      for (int g = 0; g < 2; ++g)
        #pragma unroll
        for (int ni = 0; ni < 4; ++ni) acc[g][ni] = (f32x4){0.f, 0.f, 0.f, 0.f};

      const int xl = (lane & 31) * 16;             // byte off within 512B chunk
      const int rhalf = lane >> 5;                 // 0/1: which row of the pair

      for (int k0 = 0; k0 < D; k0 += 128) {
        // ---- stage: 16 instrs, each = 2 rows x 512B contiguous ----
        #pragma unroll
        for (int ii = 0; ii < 16; ++ii) {
          int rl = ii * 2 + rhalf;                 // local row 0..31
          int grow = rowbase + rl;
          if (grow >= nrows) grow = nrows - 1;     // clamp; stores guarded
          int off = xl ^ ((rl & 7) << 4);          // pre-swizzled source (m173)
          gload_lds16(feat + (size_t)grow * D + k0 + (off >> 2),
                      wpan + ii * 256);            // linear LDS dest (2 rows)
        }
        asm volatile("s_waitcnt vmcnt(0)" ::: "memory");
        // ---- compute 4 x 32-k sub-iters from the panel ----
        const int l0 = m_lo, l1 = m_lo + 16;
        const int sz0 = (l0 & 7) << 4;             // (l1&7)==(l0&7)
        #pragma unroll
        for (int kk = 0; kk < 4; ++kk) {
          int boff = kk * 128 + q * 32;
          float4 lo0 = *(const float4*)(wpanb + l0 * 512 + ((boff) ^ sz0));
          float4 hi0 = *(const float4*)(wpanb + l0 * 512 + ((boff + 16) ^ sz0));
          float4 lo1 = *(const float4*)(wpanb + l1 * 512 + ((boff) ^ sz0));
          float4 hi1 = *(const float4*)(wpanb + l1 * 512 + ((boff + 16) ^ sz0));
          const short* Bpp = Wb + (size_t)m_lo * D + k0 + kk * 32 + q * 8;
          s16x8 b0 = *(const s16x8*)(Bpp);
          s16x8 b1 = *(const s16x8*)(Bpp + (size_t)16 * D);
          s16x8 b2 = *(const s16x8*)(Bpp + (size_t)32 * D);
          s16x8 b3 = *(const s16x8*)(Bpp + (size_t)48 * D);
          union { s16x8 v; unsigned u[4]; } av0, av1;
          av0.u[0] = pk2(lo0.x, lo0.y); av0.u[1] = pk2(lo0.z, lo0.w);
          av0.u[2] = pk2(hi0.x, hi0.y); av0.u[3] = pk2(hi0.z, hi0.w);
          av1.u[0] = pk2(lo1.x, lo1.y); av1.u[1] = pk2(lo1.z, lo1.w);
          av1.u[2] = pk2(hi1.x, hi1.y); av1.u[3] = pk2(hi1.z, hi1.w);
          acc[0][0] = __builtin_amdgcn_mfma_f32_16x16x32_bf16(av0.v, b0, acc[0][0], 0, 0, 0);
          acc[0][1] = __builtin_amdgcn_mfma_f32_16x16x32_bf16(av0.v, b1, acc[0][1], 0, 0, 0);
          acc[0][2] = __builtin_amdgcn_mfma_f32_16x16x32_bf16(av0.v, b2, acc[0][2], 0, 0, 0);
          acc[0][3] = __builtin_amdgcn_mfma_f32_16x16x32_bf16(av0.v, b3, acc[0][3], 0, 0, 0);
          acc[1][0] = __builtin_amdgcn_mfma_f32_16x16x32_bf16(av1.v, b0, acc[1][0], 0, 0, 0);
          acc[1][1] = __builtin_amdgcn_mfma_f32_16x16x32_bf16(av1.v, b1, acc[1][1], 0, 0, 0);
          acc[1][2] = __builtin_amdgcn_mfma_f32_16x16x32_bf16(av1.v, b2, acc[1][2], 0, 0, 0);
          acc[1][3] = __builtin_amdgcn_mfma_f32_16x16x32_bf16(av1.v, b3, acc[1][3], 0, 0, 0);
        }
        // panel reads done in-wave; next stage overwrite is same-wave safe
      }

      float bias_v[4];
      #pragma unroll
      for (int ni = 0; ni < 4; ++ni) {
        int col = ni * 16 + m_lo;
        bias_v[ni] = (col < V) ? bias[col] : 0.f;
      }

      // C/D layout: col = lane&15, row = (lane>>4)*4 + reg   [m89-verified]
      #pragma unroll
      for (int g = 0; g < 2; ++g) {
        #pragma unroll
        for (int r = 0; r < 4; ++r) {
          int grow = rowbase + g * 16 + q * 4 + r;
          float lg[4];
          #pragma unroll
          for (int ni = 0; ni < 4; ++ni) {
            int col = ni * 16 + m_lo;
            lg[ni] = (col < V) ? (acc[g][ni][r] + bias_v[ni]) : -1e30f;
          }
          float m = fmaxf(fmaxf(lg[0], lg[1]), fmaxf(lg[2], lg[3]));
          #pragma unroll
          for (int off = 1; off < 16; off <<= 1) m = fmaxf(m, __shfl_xor(m, off));
          float p[4];
          #pragma unroll
          for (int ni = 0; ni < 4; ++ni) p[ni] = exp2f((lg[ni] - m) * LOG2E);
          float s = (p[0] + p[1]) + (p[2] + p[3]);
          #pragma unroll
          for (int off = 1; off < 16; off <<= 1) s += __shfl_xor(s, off);

          if (grow < rowlim) {
            float* orow = pt + (size_t)grow * 64;
            orow[m_lo] = p[0];
            orow[16 + m_lo] = p[1];
            orow[32 + m_lo] = p[2];
            if (m_lo < 8)       orow[48 + m_lo] = p[3];
            else if (m_lo == 8) orow[56] = logf(s);        // K_t (ln units)
            else if (m_lo == 9) orow[57] = s * INV_E;      // star~ emission
            else                orow[48 + m_lo] = 0.f;     // cols 58..63
          }
        }
      }

      __syncthreads();               // all 4 waves' pt stores issued+drained
      if (threadIdx.x == 0)
        __hip_atomic_store(&flags[b * CPB + c], 1, __ATOMIC_RELEASE,
                           __HIP_MEMORY_SCOPE_AGENT);
    }
    return;
  }

  // ============ consumer: star-CTC DP (r1 bperm version, 256B rows) ========
  if (threadIdx.x >= 64) return;
  const int n = blockIdx.x;
  const int lane = threadIdx.x;
  const float* row = pt + (size_t)n * T * 64;
  const int len = in_len[n];
  const int tl = tgt_len[n];
  const int* tg = targets + (size_t)n * S;
  const int* fl = flags + n * CPB;

  int cdone = -1;
#define WAITC(cc)                                                            \
  do {                                                                       \
    int _c = (cc);                                                           \
    if (cdone < _c) {                                                        \
      while (cdone < _c) {                                                   \
        if (__hip_atomic_load((int*)&fl[cdone + 1], __ATOMIC_RELAXED,        \
                              __HIP_MEMORY_SCOPE_AGENT))                     \
          ++cdone;                                                           \
        else                                                                 \
          __builtin_amdgcn_s_sleep(2);                                       \
      }                                                                      \
      __builtin_amdgcn_fence(__ATOMIC_ACQUIRE, "agent");                     \
    }                                                                        \
  } while (0)

  const int s0 = lane * 4;
  int lab1 = (s0     < S) ? tg[s0]     : 0;
  int lab3 = (s0 + 1 < S) ? tg[s0 + 1] : 0;
  int lab5 = (s0 + 2 < S) ? tg[s0 + 2] : 0;
  int lab7 = (s0 + 3 < S) ? tg[s0 + 3] : 0;
  int labm1 = __shfl_up(lab7, 1);                // label of state 8k-1
  int labm3 = __shfl_up(lab5, 1);                // label of state 8k-3
  const bool sk1 = (lane > 0) && (lab1 != labm1);
  const bool sk3 = (lab3 != lab1);
  const bool sk5 = (lab5 != lab3);
  const bool sk7 = (lab7 != lab5);
  const bool skm1 = (labm1 != labm3);
  const int ad1 = lab1 << 2, ad3 = lab3 << 2, ad5 = lab5 << 2, ad7 = lab7 << 2;
  const int adm1 = labm1 << 2;

  float a0 = 0, a1 = 0, a2 = 0, a3 = 0, a4 = 0, a5 = 0, a6 = 0, a7 = 0, a8 = 0;
  float m1 = 0.f, m2 = 0.f, m3 = 0.f;
  int eps = 0, eL = 0;
  bool act = (lane == 0);

#define ROWL(t) row[(size_t)(((t) < len) ? (t) : (len - 1)) * 64 + lane]

  WAITC(0);                                      // rows 0..8 live in chunk 0

  // t = 0
  float rc = row[lane];
  {
    float star = rdlane(rc, 57);
    float e1i = bperm(rc, ad1);
    if (lane == 0) { a0 = star; a1 = e1i; }
  }
  float ksum = rc;

  // prefetch ring: rows 1..8
  float rr0 = ROWL(1), rr1 = ROWL(2), rr2 = ROWL(3), rr3 = ROWL(4);
  float rr4 = ROWL(5), rr5 = ROWL(6), rr6 = ROWL(7), rr7 = ROWL(8);

  // emissions for first pair (t=1,2)
  float es0v = rdlane(rr0, 57);
  float e1a = bperm(rr0, ad1), e3a = bperm(rr0, ad3);
  float e5a = bperm(rr0, ad5), e7a = bperm(rr0, ad7);
  float em1a = bperm(rr0, adm1);
  float es1v = rdlane(rr1, 57);
  float e1b = bperm(rr1, ad1), e3b = bperm(rr1, ad3);
  float e5b = bperm(rr1, ad5), e7b = bperm(rr1, ad7);

#define RENORM()                                                             \
  do {                                                                       \
    float mx = fmaxf(fmaxf(fmaxf(a0, a1), fmaxf(a2, a3)),                    \
                     fmaxf(fmaxf(a4, a5), fmaxf(a6, a7)));                   \
    mx = fmaxf(mx, a8);                                                      \
    int e = (int)((__float_as_uint(mx) >> 23) & 255) - 126;                  \
    e = (act && mx > 0.f) ? e : 0;                                           \
    a0 = ldexpf(a0, -e); a1 = ldexpf(a1, -e); a2 = ldexpf(a2, -e);           \
    a3 = ldexpf(a3, -e); a4 = ldexpf(a4, -e); a5 = ldexpf(a5, -e);           \
    a6 = ldexpf(a6, -e); a7 = ldexpf(a7, -e); a8 = ldexpf(a8, -e);           \
    eps += e;                                                                \
  } while (0)

#define PAIR(C0, C1, N0, N1, P0, P1, DOREN)                                  \
  do {                                                                       \
    ksum += C0; ksum += C1;                                                  \
    if (!act) eps = eL;                                                      \
    bool inc = (lane != 0) &&                                                \
               ((m1 != 0.f) || (m2 != 0.f) || (m3 != 0.f));                  \
    int d = inc ? (eL - eps) : 0;                                            \
    if (__builtin_expect(d > 24, 0)) {            /* raise own frame */      \
      a0 = ldexpf(a0, -d); a1 = ldexpf(a1, -d); a2 = ldexpf(a2, -d);         \
      a3 = ldexpf(a3, -d); a4 = ldexpf(a4, -d); a5 = ldexpf(a5, -d);         \
      a6 = ldexpf(a6, -d); a7 = ldexpf(a7, -d); a8 = ldexpf(a8, -d);         \
      eps += d;                                   /* m stay in frame eL */   \
    } else {                                                                 \
      m1 = ldexpf(m1, d); m2 = ldexpf(m2, d); m3 = ldexpf(m3, d);            \
    }                                                                        \
    act = act || (m1 != 0.f) || (m2 != 0.f) || (m3 != 0.f);                  \
    /* sub-step 1 (in-place top-down; uses old lower states) */              \
    a8 = (a8 + a7) * es0v;                                                   \
    a7 = (a7 + a6 + (sk7 ? a5 : 0.f)) * e7a;                                 \
    a6 = (a6 + a5) * es0v;                                                   \
    a5 = (a5 + a4 + (sk5 ? a3 : 0.f)) * e5a;                                 \
    a4 = (a4 + a3) * es0v;                                                   \
    a3 = (a3 + a2 + (sk3 ? a1 : 0.f)) * e3a;                                 \
    a2 = (a2 + a1) * es0v;                                                   \
    a1 = (a1 + a0 + (sk1 ? m1 : 0.f)) * e1a;                                 \
    a0 = (a0 + m1) * es0v;                                                   \
    m1 = (m1 + m2 + (skm1 ? m3 : 0.f)) * em1a;                               \
    /* sub-step 2 */                                                         \
    a8 = (a8 + a7) * es1v;                                                   \
    a7 = (a7 + a6 + (sk7 ? a5 : 0.f)) * e7b;                                 \
    a6 = (a6 + a5) * es1v;                                                   \
    a5 = (a5 + a4 + (sk5 ? a3 : 0.f)) * e5b;                                 \
    a4 = (a4 + a3) * es1v;                                                   \
    a3 = (a3 + a2 + (sk3 ? a1 : 0.f)) * e3b;                                 \
    a2 = (a2 + a1) * es1v;                                                   \
    a1 = (a1 + a0 + (sk1 ? m1 : 0.f)) * e1b;                                 \
    a0 = (a0 + m1) * es1v;                                                   \
    C0 = ROWL(P0); C1 = ROWL(P1);                 /* refill ring slots */    \
    if (DOREN) RENORM();                                                     \
    /* gathers for next pair FIRST (in-order DS: partial waits possible) */  \
    es0v = rdlane(N0, 57);                                                   \
    e1a = bperm(N0, ad1); e3a = bperm(N0, ad3);                              \
    e5a = bperm(N0, ad5); e7a = bperm(N0, ad7);                              \
    em1a = bperm(N0, adm1);                                                  \
    es1v = rdlane(N1, 57);                                                   \
    e1b = bperm(N1, ad1); e3b = bperm(N1, ad3);                              \
    e5b = bperm(N1, ad5); e7b = bperm(N1, ad7);                              \
    /* boundary shuffles (states 8k-3..8k-1 + frame) */                      \
    m3 = __shfl_up(a5, 1); m2 = __shfl_up(a6, 1); m1 = __shfl_up(a7, 1);     \
    eL = __shfl_up(eps, 1);                                                  \
    if (lane == 0) { m1 = 0.f; m2 = 0.f; m3 = 0.f; }                         \
  } while (0)

  int t0 = 1;
  for (; t0 + 8 <= len; t0 += 8) {
    int tmax = t0 + 15;
    if (tmax > len - 1) tmax = len - 1;
    WAITC(tmax >> 7);                            // gate ring refills t0+8..+15
    PAIR(rr0, rr1, rr2, rr3, t0 + 8,  t0 + 9,  false);
    PAIR(rr2, rr3, rr4, rr5, t0 + 10, t0 + 11, false);
    PAIR(rr4, rr5, rr6, rr7, t0 + 12, t0 + 13, false);
    PAIR(rr6, rr7, rr0, rr1, t0 + 14, t0 + 15, true);  // t0+7 == 0 mod 8
  }

  WAITC((len - 1) >> 7);                         // cover tail reads

  // tail: <= 7 single steps (m1/eL re-shuffled each step)
  for (int t = t0; t < len; ++t) {
    float cur = ROWL(t);
    float esv = rdlane(cur, 57);
    float e1v = bperm(cur, ad1), e3v = bperm(cur, ad3);
    float e5v = bperm(cur, ad5), e7v = bperm(cur, ad7);
    ksum += cur;
    if (!act) eps = eL;
    bool inc = (lane != 0) && (m1 != 0.f);
    int d = inc ? (eL - eps) : 0;
    float m1s;
    if (__builtin_expect(d > 24, 0)) {
      a0 = ldexpf(a0, -d); a1 = ldexpf(a1, -d); a2 = ldexpf(a2, -d);
      a3 = ldexpf(a3, -d); a4 = ldexpf(a4, -d); a5 = ldexpf(a5, -d);
      a6 = ldexpf(a6, -d); a7 = ldexpf(a7, -d); a8 = ldexpf(a8, -d);
      eps += d; m1s = m1;
    } else {
      m1s = inc ? ldexpf(m1, d) : 0.f;
    }
    act = act || (m1s != 0.f);
    a8 = (a8 + a7) * esv;
    a7 = (a7 + a6 + (sk7 ? a5 : 0.f)) * e7v;
    a6 = (a6 + a5) * esv;
    a5 = (a5 + a4 + (sk5 ? a3 : 0.f)) * e5v;
    a4 = (a4 + a3) * esv;
    a3 = (a3 + a2 + (sk3 ? a1 : 0.f)) * e3v;
    a2 = (a2 + a1) * esv;
    a1 = (a1 + a0 + (sk1 ? m1s : 0.f)) * e1v;
    a0 = (a0 + m1s) * esv;
    if ((t & 7) == 0) RENORM();
    m1 = __shfl_up(a7, 1);
    eL = __shfl_up(eps, 1);
    if (lane == 0) m1 = 0.f;
  }

  // final reduce — all cross-lane via shfl (no LDS / no barrier)
  int last = 2 * tl;
  int kx = last >> 3, jx = last & 7;
  if (kx > 63) { kx = 63; jx = last - 504; }     // state 512 -> lane63 a8
  int ky = (last - 1) >> 3, jy = (last - 1) & 7;
  float vx = pick9(jx, a0, a1, a2, a3, a4, a5, a6, a7, a8);
  float vy = pick9(jy, a0, a1, a2, a3, a4, a5, a6, a7, a8);
  float k56 = __shfl(ksum, 56);
  float sx = __shfl(vx, kx); int ex = __shfl(eps, kx);
  float sy = __shfl(vy, ky); int ey = __shfl(eps, ky);
  if (lane == 0) {
    int em = (ex > ey) ? ex : ey;
    float v = ldexpf(sx, ex - em) + ldexpf(sy, ey - em);
    float score = logf(v) + (float)em * LN2f - k56;
    partial[n] = -score / (float)tl;
  }
#undef WAITC
#undef ROWL
#undef RENORM
#undef PAIR
}

// ---------------------------------------------------------------------------
// Kernel 3: mean over batch
// ---------------------------------------------------------------------------
__global__ void reduce_mean(const float* __restrict__ partial,
                            float* __restrict__ out, int B) {
  float v = 0.f;
  for (int i = threadIdx.x; i < B; i += 64) v += partial[i];
  #pragma unroll
  for (int off = 32; off > 0; off >>= 1) v += __shfl_down(v, off, 64);
  if (threadIdx.x == 0) out[0] = v / (float)B;
}

extern "C" void kernel_launch(void* const* d_in, const int* in_sizes, int n_in,
                              void* d_out, int out_size, void* d_ws, size_t ws_size,
                              hipStream_t stream) {
  const float* feat = (const float*)d_in[0];
  const float* W = (const float*)d_in[1];
  const float* bias = (const float*)d_in[2];
  const int* targets = (const int*)d_in[3];
  const int* in_len = (const int*)d_in[4];
  const int* tgt_len = (const int*)d_in[5];
  float* out = (float*)d_out;

  const int V = in_sizes[2];
  const int D = in_sizes[1] / V;
  const int B = in_sizes[4];
  const int T = in_sizes[0] / (B * D);
  const int S = in_sizes[3] / B;
  const int nrows = B * T;

  float* pt = (float*)d_ws;                         // nrows*64 fp32 (32 MB)
  float* partial = pt + (size_t)nrows * 64;         // B fp32
  short* Wb = (short*)(partial + B);                // 64*D bf16
  const int CPB = (T + 127) / 128;                  // time-chunks per batch
  int* flags = (int*)((char*)Wb + (size_t)64 * D * sizeof(short));  // B*CPB

  conv_w<<<(64 * D + 255) / 256, 256, 0, stream>>>(W, Wb, V, D,
                                                   flags, B * CPB);

  // grid = B consumers + 128 persistent producers (c-major wavefront:
  // 4 tiles each; chunks 0-3 ready after round 0 while DP streams behind).
  const int NTILES = B * CPB;
  int NPROD = 128;
  if (NPROD > NTILES) NPROD = NTILES;
  fused_gemm_star<<<dim3(B + NPROD), 256, 0, stream>>>(
      feat, Wb, bias, pt, flags, targets, in_len, tgt_len, partial,
      nrows, D, V, T, S, B, CPB);

  reduce_mean<<<1, 64, 0, stream>>>(partial, out, B);
}